// Round 12
// baseline (233.027 us; speedup 1.0000x reference)
//
#include <hip/hip_runtime.h>

// ---------------------------------------------------------------------------
// 2-layer GCN + global mean pool, MI355X (gfx950).
//   A_hat = D^{-1/2}(A+I)D^{-1/2}
//   G' = dinv*(X @ W1) fp16 [MFMA];  H'' = dinv*relu(dinv*A_sum(G')+b1) fp16
//   out = pool(dinv*A_sum(H'')) @ W2 + b2
// R12: (1) UNFUSE fill from GEMM: R11 showed the fused dispatch at 47us with
//     WRITE_SIZE 55MB (vs 15MB useful) - the GEMM's 25MB streaming traffic
//     evicted partially-filled colidx lines from L2, amplifying the 4B
//     scatter writes to full-line HBM writes. Fill alone keeps its 2.9MB
//     working set L2-resident. (2) aggs back to R10 per-node form (R11 flat
//     stream was net negative).
// ---------------------------------------------------------------------------

#define D 128
#define NGRAPH 64
#define SCAN_B 1024
#define AGG_BLOCKS 2048   // 8192 waves = 32/CU

typedef _Float16 h16x2 __attribute__((ext_vector_type(2)));
typedef _Float16 f16x8 __attribute__((ext_vector_type(8)));
typedef float    f32x4 __attribute__((ext_vector_type(4)));

__device__ __forceinline__ float2 h2f(unsigned u) {
    h16x2 h = __builtin_bit_cast(h16x2, u);
    return make_float2((float)h.x, (float)h.y);
}
__device__ __forceinline__ unsigned f2h(float x, float y) {
    h16x2 h;
    h.x = (_Float16)x;
    h.y = (_Float16)y;
    return __builtin_bit_cast(unsigned, h);
}

// --- diagnostic: all-zero output (ws too small) ----------------------------
__global__ void zero_out_kernel(float* __restrict__ out, int n) {
    int i = blockIdx.x * blockDim.x + threadIdx.x;
    if (i < n) out[i] = 0.f;
}

// --- Fused: X->fp16 conversion | W1->fp16 MFMA-B pack | degree count -------
__global__ __launch_bounds__(256) void conv_count_kernel(const float* __restrict__ X,
                                                         _Float16* __restrict__ Xh,
                                                         const float* __restrict__ W1,
                                                         _Float16* __restrict__ WB,
                                                         const int* __restrict__ ei,
                                                         int* __restrict__ deg,
                                                         int N, int E, int cb) {
    int b = (int)blockIdx.x;
    if (b < cb) {
        int idx = b * 256 + (int)threadIdx.x;     // float4 index
        int total = N * (D / 4);
        if (idx < total) {
            float4 v = ((const float4*)X)[idx];
            uint2 o;
            o.x = f2h(v.x, v.y);
            o.y = f2h(v.z, v.w);
            ((uint2*)Xh)[idx] = o;
        }
        return;
    }
    if (b < cb + 8) {
        // WB[((kt*8+nt)*64+lane)*8+j] = W1[(kt*32+(lane>>4)*8+j)*D + nt*16+(lane&15)]
        int idx = (b - cb) * 256 + (int)threadIdx.x;   // 0..2047
        int lane = idx & 63;
        int nt   = (idx >> 6) & 7;
        int kt   = idx >> 9;
        int col  = nt * 16 + (lane & 15);
        int krow = kt * 32 + (lane >> 4) * 8;
#pragma unroll
        for (int j = 0; j < 8; ++j)
            WB[idx * 8 + j] = (_Float16)W1[(krow + j) * D + col];
        return;
    }
    int e = (b - cb - 8) * 256 + (int)threadIdx.x;
    if (e < E) {
        int d = ei[E + e];
        if (d >= 0 && d < N) atomicAdd(&deg[d], 1);
    }
}

// per-block scan of deg -> local exclusive prefix; also emits dinv.
__global__ __launch_bounds__(SCAN_B) void block_scan_kernel(const int* __restrict__ deg,
                                                            int* __restrict__ rowstart,
                                                            int* __restrict__ bsum,
                                                            float* __restrict__ dinv,
                                                            int N) {
    __shared__ int sc[SCAN_B];
    int t = threadIdx.x;
    int i = blockIdx.x * SCAN_B + t;
    int orig = (i < N) ? deg[i] : 0;
    int v = orig;
    sc[t] = v;
    __syncthreads();
    for (int off = 1; off < SCAN_B; off <<= 1) {
        int add = (t >= off) ? sc[t - off] : 0;
        __syncthreads();
        v += add;
        sc[t] = v;
        __syncthreads();
    }
    if (i < N) {
        rowstart[i] = v - orig;                      // local exclusive
        dinv[i]     = rsqrtf((float)orig + 1.0f);    // +1 self loop
    }
    if (t == SCAN_B - 1) bsum[blockIdx.x] = v;
}

// each block self-computes its bsum prefix (nblk<=64) -> no scan_sums kernel.
__global__ __launch_bounds__(SCAN_B) void finalize_scan_kernel(const int* __restrict__ bsum,
                                                               int* __restrict__ rowstart,
                                                               int* __restrict__ cursor,
                                                               int N, int nblk, int E) {
    __shared__ int s_off;
    if (threadIdx.x < 64) {
        int lane = (int)threadIdx.x;
        int v = (lane < nblk && lane < (int)blockIdx.x) ? bsum[lane] : 0;
        for (int off = 32; off > 0; off >>= 1) v += __shfl_down(v, off);
        if (lane == 0) s_off = v;
    }
    __syncthreads();
    int i = blockIdx.x * SCAN_B + threadIdx.x;
    if (i < N) {
        int rs = rowstart[i] + s_off;
        rowstart[i] = rs;
        cursor[i]   = rs;
    }
    if (blockIdx.x == 0 && threadIdx.x == 0) rowstart[N] = E;
}

// --- CSR fill (own dispatch: colidx working set stays L2-resident) ----------
__global__ void fill_kernel(const int* __restrict__ ei, int* __restrict__ cursor,
                            int* __restrict__ colidx, int E, int N) {
    int e = blockIdx.x * blockDim.x + threadIdx.x;
    if (e < E) {
        int d = ei[E + e];
        if (d >= 0 && d < N) {
            int slot = atomicAdd(&cursor[d], 1);
            if (slot >= 0 && slot < E) {
                int s = ei[e];
                colidx[slot] = min(max(s, 0), N - 1);
            }
        }
    }
}

// --- MFMA GEMM: G' = dinv*(Xh @ W1h), fp16 out ------------------------------
__global__ __launch_bounds__(256) void gemm_kernel(const _Float16* __restrict__ Xh,
                                                   const _Float16* __restrict__ WB,
                                                   const float* __restrict__ dinv,
                                                   _Float16* __restrict__ Gh,
                                                   int N) {
    int t = (int)threadIdx.x;
    int wave = t >> 6, lane = t & 63;
    int mbase = blockIdx.x * 64 + wave * 16;
    int arow  = mbase + (lane & 15);
    if (arow >= N) arow = N - 1;             // clamped duplicate reads
    int kgrp  = lane >> 4;                   // 0..3

    f16x8 afrag[4];
#pragma unroll
    for (int kt = 0; kt < 4; ++kt) {
        uint4 u = *(const uint4*)(Xh + (size_t)arow * D + kt * 32 + kgrp * 8);
        afrag[kt] = __builtin_bit_cast(f16x8, u);
    }
    f32x4 acc[8];
#pragma unroll
    for (int nt = 0; nt < 8; ++nt) acc[nt] = (f32x4){0.f, 0.f, 0.f, 0.f};
#pragma unroll
    for (int kt = 0; kt < 4; ++kt) {
#pragma unroll
        for (int nt = 0; nt < 8; ++nt) {
            uint4 u = *(const uint4*)(WB + (((kt * 8 + nt) * 64 + lane) * 8));
            f16x8 bfrag = __builtin_bit_cast(f16x8, u);
            acc[nt] = __builtin_amdgcn_mfma_f32_16x16x32_f16(afrag[kt], bfrag, acc[nt], 0, 0, 0);
        }
    }
    // C/D: col = lane&15, row = kgrp*4 + reg   [m89-verified, dtype-indep]
    int r0 = mbase + kgrp * 4;
#pragma unroll
    for (int r = 0; r < 4; ++r) {
        int row = r0 + r;
        if (row < N) {
            float dv = dinv[row];
#pragma unroll
            for (int nt = 0; nt < 8; ++nt)
                Gh[(size_t)row * D + nt * 16 + (lane & 15)] = (_Float16)(dv * acc[nt][r]);
        }
    }
}

// --- agg1: H''_i = dinv_i * relu(dinv_i*(sum_e G'_s + G'_i) + b1), fp16 -----
// 64-lane wave per node (uniform loop); unroll-8 outstanding 256B gathers.
__global__ __launch_bounds__(256) void agg1_kernel(const unsigned* __restrict__ Gh,
                                                   const int* __restrict__ rowstart,
                                                   const int* __restrict__ colidx,
                                                   const float* __restrict__ dinv,
                                                   const float* __restrict__ b1,
                                                   unsigned* __restrict__ Hh,
                                                   int N, int chunk) {
    int gid  = blockIdx.x * 4 + (threadIdx.x >> 6);
    int lane = threadIdx.x & 63;
    int i0 = gid * chunk, i1 = min(i0 + chunk, N);
    float bx = b1[2 * lane], by = b1[2 * lane + 1];
    for (int i = i0; i < i1; ++i) {
        float di = dinv[i];
        float2 acc = h2f(Gh[(size_t)i * (D / 2) + lane]);   // self term
        int e0 = rowstart[i], e1 = rowstart[i + 1];
        int e = e0;
        for (; e + 7 < e1; e += 8) {
            unsigned u[8];
#pragma unroll
            for (int j = 0; j < 8; ++j)
                u[j] = Gh[(size_t)colidx[e + j] * (D / 2) + lane];
#pragma unroll
            for (int j = 0; j < 8; ++j) {
                float2 v = h2f(u[j]);
                acc.x += v.x;
                acc.y += v.y;
            }
        }
        for (; e + 3 < e1; e += 4) {
            unsigned u[4];
#pragma unroll
            for (int j = 0; j < 4; ++j)
                u[j] = Gh[(size_t)colidx[e + j] * (D / 2) + lane];
#pragma unroll
            for (int j = 0; j < 4; ++j) {
                float2 v = h2f(u[j]);
                acc.x += v.x;
                acc.y += v.y;
            }
        }
        for (; e < e1; ++e) {
            float2 v = h2f(Gh[(size_t)colidx[e] * (D / 2) + lane]);
            acc.x += v.x;
            acc.y += v.y;
        }
        float hx = fmaxf(fmaf(di, acc.x, bx), 0.f) * di;    // H'' = dinv*relu
        float hy = fmaxf(fmaf(di, acc.y, by), 0.f) * di;
        Hh[(size_t)i * (D / 2) + lane] = f2h(hx, hy);
    }
}

// --- agg2 + pool: pool[batch_i] += dinv_i*(sum_e H''_s + H''_i) -------------
__global__ __launch_bounds__(256) void agg2_pool_kernel(const unsigned* __restrict__ Hh,
                                                        const int* __restrict__ rowstart,
                                                        const int* __restrict__ colidx,
                                                        const float* __restrict__ dinv,
                                                        const int* __restrict__ batch,
                                                        float* __restrict__ pool,
                                                        int N, int chunk) {
    int gid  = blockIdx.x * 4 + (threadIdx.x >> 6);
    int lane = threadIdx.x & 63;
    int i0 = gid * chunk, i1 = min(i0 + chunk, N);
    if (i0 >= N) return;

    float2 pa = make_float2(0.f, 0.f);
    int cur = min(max(batch[i0], 0), NGRAPH - 1);
    for (int i = i0; i < i1; ++i) {
        float di = dinv[i];
        float2 a = h2f(Hh[(size_t)i * (D / 2) + lane]);     // self term
        int e0 = rowstart[i], e1 = rowstart[i + 1];
        int e = e0;
        for (; e + 7 < e1; e += 8) {
            unsigned u[8];
#pragma unroll
            for (int j = 0; j < 8; ++j)
                u[j] = Hh[(size_t)colidx[e + j] * (D / 2) + lane];
#pragma unroll
            for (int j = 0; j < 8; ++j) {
                float2 v = h2f(u[j]);
                a.x += v.x;
                a.y += v.y;
            }
        }
        for (; e + 3 < e1; e += 4) {
            unsigned u[4];
#pragma unroll
            for (int j = 0; j < 4; ++j)
                u[j] = Hh[(size_t)colidx[e + j] * (D / 2) + lane];
#pragma unroll
            for (int j = 0; j < 4; ++j) {
                float2 v = h2f(u[j]);
                a.x += v.x;
                a.y += v.y;
            }
        }
        for (; e < e1; ++e) {
            float2 v = h2f(Hh[(size_t)colidx[e] * (D / 2) + lane]);
            a.x += v.x;
            a.y += v.y;
        }
        int b = min(max(batch[i], 0), NGRAPH - 1);
        if (b != cur) {
            atomicAdd(&pool[(size_t)cur * D + 2 * lane], pa.x);
            atomicAdd(&pool[(size_t)cur * D + 2 * lane + 1], pa.y);
            pa = make_float2(0.f, 0.f);
            cur = b;
        }
        pa.x = fmaf(di, a.x, pa.x);
        pa.y = fmaf(di, a.y, pa.y);
    }
    atomicAdd(&pool[(size_t)cur * D + 2 * lane], pa.x);
    atomicAdd(&pool[(size_t)cur * D + 2 * lane + 1], pa.y);
}

// --- Final tiny GEMM: out[g][o] = (pool[g]/cnt_g) . W2[:,o] + b2[o] ---------
__device__ __forceinline__ int lbound(const int* __restrict__ a, int n, int v) {
    int lo = 0, hi = n;
    while (lo < hi) {
        int m = (lo + hi) >> 1;
        if (a[m] < v) lo = m + 1; else hi = m;
    }
    return lo;
}

__global__ void final_gemm_kernel(const float* __restrict__ pool,
                                  const int* __restrict__ batch,
                                  const float* __restrict__ W2,
                                  const float* __restrict__ b2,
                                  float* __restrict__ out, int N) {
    int g = blockIdx.x, o = threadIdx.x;
    int s = lbound(batch, N, g);
    int e = lbound(batch, N, g + 1);
    float inv_cnt = 1.0f / fmaxf((float)(e - s), 1.0f);
    float acc = 0.f;
#pragma unroll 4
    for (int k = 0; k < D; ++k)
        acc = fmaf(pool[g * D + k], W2[k * D + o], acc);
    out[g * D + o] = acc * inv_cnt + b2[o];
}

// ---------------------------------------------------------------------------

extern "C" void kernel_launch(void* const* d_in, const int* in_sizes, int n_in,
                              void* d_out, int out_size, void* d_ws, size_t ws_size,
                              hipStream_t stream) {
    const float* x     = (const float*)d_in[0];
    const int*   ei    = (const int*)  d_in[1];
    const int*   batch = (const int*)  d_in[2];
    const float* W1    = (const float*)d_in[3];
    const float* b1    = (const float*)d_in[4];
    const float* W2    = (const float*)d_in[5];
    const float* b2    = (const float*)d_in[6];
    float* out = (float*)d_out;

    const int N = in_sizes[0] / D;
    const int E = in_sizes[1] / 2;
    const int nblk = (N + SCAN_B - 1) / SCAN_B;   // <=64 for N<=65536

    // workspace carve-up (256B aligned); deg+pool adjacent -> single memset
    char* ws = (char*)d_ws;
    size_t off = 0;
    auto carve = [&](size_t bytes) {
        size_t o = off;
        off = (off + bytes + 255) & ~(size_t)255;
        return o;
    };
    size_t o_deg      = carve((size_t)N * 4);
    size_t o_pool     = carve((size_t)NGRAPH * D * 4);
    size_t zspan      = off;                       // memset [0, zspan)
    size_t o_rowstart = carve((size_t)(N + 1) * 4);
    size_t o_cursor   = carve((size_t)(N + 1) * 4);
    size_t o_dinv     = carve((size_t)N * 4);
    size_t o_colidx   = carve((size_t)E * 4);
    size_t o_bsum     = carve((size_t)64 * 4);
    size_t o_xh       = carve((size_t)N * D * 2);  // fp16 X
    size_t o_wb       = carve((size_t)D * D * 2);  // fp16 W1 (MFMA B order)
    size_t o_gh       = carve((size_t)N * D * 2);  // fp16 G'
    size_t o_hh       = carve((size_t)N * D * 2);  // fp16 H''
    size_t need = off;

    if (ws_size < need) {
        zero_out_kernel<<<(out_size + 255) / 256, 256, 0, stream>>>(out, out_size);
        return;
    }

    int*       deg      = (int*)      (ws + o_deg);
    float*     pool     = (float*)    (ws + o_pool);
    int*       rowstart = (int*)      (ws + o_rowstart);
    int*       cursor   = (int*)      (ws + o_cursor);
    float*     dinv     = (float*)    (ws + o_dinv);
    int*       colidx   = (int*)      (ws + o_colidx);
    int*       bsum     = (int*)      (ws + o_bsum);
    _Float16*  Xh       = (_Float16*) (ws + o_xh);
    _Float16*  WB       = (_Float16*) (ws + o_wb);
    _Float16*  Gh       = (_Float16*) (ws + o_gh);
    _Float16*  Hh       = (_Float16*) (ws + o_hh);

    hipMemsetAsync(ws, 0, zspan, stream);          // deg + pool in one shot

    int eb = (E + 255) / 256;
    int gb = (N + 63) / 64;
    int cb = (N * (D / 4) + 255) / 256;            // X float4-groups

    conv_count_kernel<<<cb + 8 + eb, 256, 0, stream>>>(x, Xh, W1, WB, ei, deg, N, E, cb);
    block_scan_kernel<<<nblk, SCAN_B, 0, stream>>>(deg, rowstart, bsum, dinv, N);
    finalize_scan_kernel<<<nblk, SCAN_B, 0, stream>>>(bsum, rowstart, cursor, N, nblk, E);
    // fill ALONE: colidx's 2.9MB working set stays L2-resident (no GEMM
    // streaming traffic evicting partially-filled lines)
    fill_kernel<<<eb, 256, 0, stream>>>(ei, cursor, colidx, E, N);
    gemm_kernel<<<gb, 256, 0, stream>>>(Xh, WB, dinv, Gh, N);

    int groups = AGG_BLOCKS * 4;
    int chunk  = (N + groups - 1) / groups;
    agg1_kernel<<<AGG_BLOCKS, 256, 0, stream>>>((const unsigned*)Gh, rowstart, colidx,
                                                dinv, b1, (unsigned*)Hh, N, chunk);
    agg2_pool_kernel<<<AGG_BLOCKS, 256, 0, stream>>>((const unsigned*)Hh, rowstart, colidx,
                                                     dinv, batch, pool, N, chunk);
    final_gemm_kernel<<<NGRAPH, D, 0, stream>>>(pool, batch, W2, b2, out, N);
}